// Round 1
// baseline (3367.730 us; speedup 1.0000x reference)
//
#include <hip/hip_runtime.h>
#include <math.h>

#define N_NODES 100000
#define FDIM 128
#define E_EDGES 1600000

// ---------------- degree ----------------
__global__ __launch_bounds__(256) void deg_kernel(const int* __restrict__ dst,
                                                  float* __restrict__ deg) {
    int e = blockIdx.x * blockDim.x + threadIdx.x;
    if (e < E_EDGES) unsafeAtomicAdd(&deg[dst[e]], 1.0f);
}

__global__ __launch_bounds__(256) void dinv_kernel(float* __restrict__ deg) {
    int i = blockIdx.x * blockDim.x + threadIdx.x;
    if (i < N_NODES) deg[i] = rsqrtf(deg[i] + 1.0f);
}

// ---------------- GEMM: H = X @ W  (X:[n,128], W:[128,128]) ----------------
#define GEMM_ROWS 32
__global__ __launch_bounds__(128) void gemm128(const float* __restrict__ X,
                                               const float* __restrict__ W,
                                               float* __restrict__ H) {
    __shared__ float Ws[128 * 128];
    __shared__ float xs[128];
    const int j = threadIdx.x;
    // cooperative load of W into LDS (coalesced)
    for (int k = 0; k < 128; ++k) Ws[k * 128 + j] = W[k * 128 + j];
    const int row0 = blockIdx.x * GEMM_ROWS;
    for (int r = 0; r < GEMM_ROWS; ++r) {
        const int row = row0 + r;
        __syncthreads();
        xs[j] = X[(size_t)row * 128 + j];
        __syncthreads();
        float acc = 0.f;
#pragma unroll
        for (int k = 0; k < 128; ++k) acc = fmaf(xs[k], Ws[k * 128 + j], acc);
        H[(size_t)row * 128 + j] = acc;
    }
}

// ---------------- init agg with self-loop: agg = h * dinv^2 ----------------
__global__ __launch_bounds__(256) void selfloop_kernel(const float* __restrict__ h,
                                                       const float* __restrict__ dinv,
                                                       float* __restrict__ agg) {
    int gid = blockIdx.x * blockDim.x + threadIdx.x;  // over N*128
    int i = gid >> 7;
    float di = dinv[i];
    agg[gid] = h[gid] * di * di;
}

// ---------------- edge scatter: agg[dst] += h[src]*norm (one wave/edge) ----
__global__ __launch_bounds__(256) void edge_kernel(const int* __restrict__ src,
                                                   const int* __restrict__ dst,
                                                   const float* __restrict__ dinv,
                                                   const float* __restrict__ h,
                                                   float* __restrict__ agg) {
    int gid = blockIdx.x * blockDim.x + threadIdx.x;
    int e = gid >> 6;
    int lane = gid & 63;
    if (e >= E_EDGES) return;
    int s = src[e], d = dst[e];
    float norm = dinv[s] * dinv[d];
    const float2 v = ((const float2*)(h + (size_t)s * 128))[lane];
    float* ap = agg + (size_t)d * 128 + lane * 2;
    unsafeAtomicAdd(ap, v.x * norm);
    unsafeAtomicAdd(ap + 1, v.y * norm);
}

// ---------------- bias + relu (in place on agg) ----------------
__global__ __launch_bounds__(256) void bias_relu_kernel(const float* __restrict__ b,
                                                        float* __restrict__ agg) {
    int gid = blockIdx.x * blockDim.x + threadIdx.x;  // over N*128
    int j = gid & 127;
    float v = agg[gid] + b[j];
    agg[gid] = fmaxf(v, 0.f);
}

// ---------------- FC (128->2) + log_softmax, one wave per node ------------
__global__ __launch_bounds__(256) void fc_kernel(const float* __restrict__ x,
                                                 const float* __restrict__ Wfc,
                                                 const float* __restrict__ bfc,
                                                 float* __restrict__ out) {
    int gid = blockIdx.x * blockDim.x + threadIdx.x;
    int node = gid >> 6;
    int lane = gid & 63;
    if (node >= N_NODES) return;
    const float2 v = ((const float2*)(x + (size_t)node * 128))[lane];
    int k0 = lane * 2;
    float a0 = v.x * Wfc[k0 * 2 + 0] + v.y * Wfc[(k0 + 1) * 2 + 0];
    float a1 = v.x * Wfc[k0 * 2 + 1] + v.y * Wfc[(k0 + 1) * 2 + 1];
#pragma unroll
    for (int off = 32; off > 0; off >>= 1) {
        a0 += __shfl_down(a0, off);
        a1 += __shfl_down(a1, off);
    }
    if (lane == 0) {
        float l0 = a0 + bfc[0];
        float l1 = a1 + bfc[1];
        float m = fmaxf(l0, l1);
        float lse = m + logf(expf(l0 - m) + expf(l1 - m));
        out[(size_t)node * 2 + 0] = l0 - lse;
        out[(size_t)node * 2 + 1] = l1 - lse;
    }
}

extern "C" void kernel_launch(void* const* d_in, const int* in_sizes, int n_in,
                              void* d_out, int out_size, void* d_ws, size_t ws_size,
                              hipStream_t stream) {
    const float* x   = (const float*)d_in[0];
    const int*   ei  = (const int*)d_in[1];
    const float* W1  = (const float*)d_in[2];
    const float* b1  = (const float*)d_in[3];
    const float* W2  = (const float*)d_in[4];
    const float* b2  = (const float*)d_in[5];
    const float* Wfc = (const float*)d_in[6];
    const float* bfc = (const float*)d_in[7];
    float* out = (float*)d_out;

    const int* src = ei;
    const int* dst = ei + E_EDGES;

    float* dinv   = (float*)d_ws;                       // N
    float* hbuf   = dinv + N_NODES;                     // N*128
    float* aggbuf = hbuf + (size_t)N_NODES * FDIM;      // N*128

    const int NE_BLK = (E_EDGES + 255) / 256;
    const int NN_BLK = (N_NODES + 255) / 256;
    const int NF_BLK = (N_NODES * FDIM) / 256;          // exact: 50000
    const int EDGE_BLK = E_EDGES / 4;                   // 64 lanes/edge, 4 edges/block

    // degree -> dinv
    hipMemsetAsync(dinv, 0, N_NODES * sizeof(float), stream);
    deg_kernel<<<NE_BLK, 256, 0, stream>>>(dst, dinv);
    dinv_kernel<<<NN_BLK, 256, 0, stream>>>(dinv);

    // ---- layer 1 ----
    gemm128<<<N_NODES / GEMM_ROWS, 128, 0, stream>>>(x, W1, hbuf);
    selfloop_kernel<<<NF_BLK, 256, 0, stream>>>(hbuf, dinv, aggbuf);
    edge_kernel<<<EDGE_BLK, 256, 0, stream>>>(src, dst, dinv, hbuf, aggbuf);
    bias_relu_kernel<<<NF_BLK, 256, 0, stream>>>(b1, aggbuf);   // aggbuf = x2

    // ---- layer 2 ----
    gemm128<<<N_NODES / GEMM_ROWS, 128, 0, stream>>>(aggbuf, W2, hbuf);
    selfloop_kernel<<<NF_BLK, 256, 0, stream>>>(hbuf, dinv, aggbuf);
    edge_kernel<<<EDGE_BLK, 256, 0, stream>>>(src, dst, dinv, hbuf, aggbuf);
    bias_relu_kernel<<<NF_BLK, 256, 0, stream>>>(b2, aggbuf);   // aggbuf = x3

    // ---- FC + log_softmax ----
    fc_kernel<<<(N_NODES * 64) / 256, 256, 0, stream>>>(aggbuf, Wfc, bfc, out);
}

// Round 2
// 1116.256 us; speedup vs baseline: 3.0170x; 3.0170x over previous
//
#include <hip/hip_runtime.h>
#include <math.h>

#define N_NODES 100000
#define FDIM 128
#define E_EDGES 1600000
#define NSCAN_BLKS ((N_NODES + 1023) / 1024)   // 98

// ---------------- in-degree histogram (int atomics) ----------------
__global__ __launch_bounds__(256) void hist_kernel(const int* __restrict__ dst,
                                                   int* __restrict__ cnt) {
    int e = blockIdx.x * blockDim.x + threadIdx.x;
    if (e < E_EDGES) atomicAdd(&cnt[dst[e]], 1);
}

// ---------------- 3-phase exclusive scan: cnt -> rowptr ----------------
__global__ __launch_bounds__(256) void scan1(const int* __restrict__ cnt,
                                             int* __restrict__ excl,
                                             int* __restrict__ bsum) {
    __shared__ int lds[256];
    const int b = blockIdx.x, t = threadIdx.x;
    const int base = b * 1024 + t * 4;
    int v[4];
#pragma unroll
    for (int q = 0; q < 4; ++q) {
        int i = base + q;
        v[q] = (i < N_NODES) ? cnt[i] : 0;
    }
    int tsum = v[0] + v[1] + v[2] + v[3];
    lds[t] = tsum;
    __syncthreads();
    for (int off = 1; off < 256; off <<= 1) {
        int x = lds[t];
        int y = (t >= off) ? lds[t - off] : 0;
        __syncthreads();
        lds[t] = x + y;
        __syncthreads();
    }
    int texcl = lds[t] - tsum;
    if (t == 255) bsum[b] = lds[t];
    int run = texcl;
#pragma unroll
    for (int q = 0; q < 4; ++q) {
        int i = base + q;
        if (i < N_NODES) excl[i] = run;
        run += v[q];
    }
}

__global__ __launch_bounds__(128) void scan2(int* __restrict__ bsum) {
    __shared__ int lds[128];
    const int t = threadIdx.x;
    int v = (t < NSCAN_BLKS) ? bsum[t] : 0;
    lds[t] = v;
    __syncthreads();
    for (int off = 1; off < 128; off <<= 1) {
        int x = lds[t];
        int y = (t >= off) ? lds[t - off] : 0;
        __syncthreads();
        lds[t] = x + y;
        __syncthreads();
    }
    if (t < NSCAN_BLKS) bsum[t] = lds[t] - v;   // exclusive
}

// add block offsets + compute dinv + close rowptr
__global__ __launch_bounds__(256) void scan3(int* __restrict__ rowptr,
                                             const int* __restrict__ bsum,
                                             const int* __restrict__ cnt,
                                             float* __restrict__ dinv) {
    int i = blockIdx.x * blockDim.x + threadIdx.x;
    if (i < N_NODES) {
        rowptr[i] += bsum[i >> 10];
        dinv[i] = rsqrtf((float)cnt[i] + 1.0f);
    }
    if (i == 0) rowptr[N_NODES] = E_EDGES;
}

// ---------------- scatter edges into dst-sorted order ----------------
__global__ __launch_bounds__(256) void scatter_kernel(const int* __restrict__ src,
                                                      const int* __restrict__ dst,
                                                      const int* __restrict__ rowptr,
                                                      int* __restrict__ cursor,
                                                      int* __restrict__ ssrc) {
    int e = blockIdx.x * blockDim.x + threadIdx.x;
    if (e >= E_EDGES) return;
    int d = dst[e];
    int p = rowptr[d] + atomicAdd(&cursor[d], 1);
    ssrc[p] = src[e];
}

// ---------------- GEMM: H = X @ W  (X:[n,128], W:[128,128]) ----------------
#define GEMM_ROWS 32
__global__ __launch_bounds__(128) void gemm128(const float* __restrict__ X,
                                               const float* __restrict__ W,
                                               float* __restrict__ H) {
    __shared__ float Ws[128 * 128];
    __shared__ float xs[128];
    const int j = threadIdx.x;
    for (int k = 0; k < 128; ++k) Ws[k * 128 + j] = W[k * 128 + j];
    const int row0 = blockIdx.x * GEMM_ROWS;
    for (int r = 0; r < GEMM_ROWS; ++r) {
        const int row = row0 + r;
        __syncthreads();
        xs[j] = X[(size_t)row * 128 + j];
        __syncthreads();
        float acc = 0.f;
#pragma unroll
        for (int k = 0; k < 128; ++k) acc = fmaf(xs[k], Ws[k * 128 + j], acc);
        H[(size_t)row * 128 + j] = acc;
    }
}

// ------- fused gather-aggregate + self-loop + bias + ReLU: one wave/node ----
__global__ __launch_bounds__(256) void agg_kernel(const int* __restrict__ rowptr,
                                                  const int* __restrict__ ssrc,
                                                  const float* __restrict__ dinv,
                                                  const float* __restrict__ h,
                                                  const float* __restrict__ bias,
                                                  float* __restrict__ out) {
    int gid = blockIdx.x * blockDim.x + threadIdx.x;
    int node = gid >> 6;
    int lane = gid & 63;
    if (node >= N_NODES) return;
    float dd = dinv[node];
    float2 v = ((const float2*)(h + (size_t)node * 128))[lane];
    float sc = dd * dd;
    float accx = v.x * sc, accy = v.y * sc;
    int j = rowptr[node];
    const int end = rowptr[node + 1];
    for (; j + 1 < end; j += 2) {
        int s0 = ssrc[j], s1 = ssrc[j + 1];
        float n0 = dinv[s0] * dd;
        float n1 = dinv[s1] * dd;
        float2 v0 = ((const float2*)(h + (size_t)s0 * 128))[lane];
        float2 v1 = ((const float2*)(h + (size_t)s1 * 128))[lane];
        accx += v0.x * n0 + v1.x * n1;
        accy += v0.y * n0 + v1.y * n1;
    }
    if (j < end) {
        int s0 = ssrc[j];
        float n0 = dinv[s0] * dd;
        float2 v0 = ((const float2*)(h + (size_t)s0 * 128))[lane];
        accx += v0.x * n0;
        accy += v0.y * n0;
    }
    float2 b = ((const float2*)bias)[lane];
    accx = fmaxf(accx + b.x, 0.f);
    accy = fmaxf(accy + b.y, 0.f);
    ((float2*)(out + (size_t)node * 128))[lane] = make_float2(accx, accy);
}

// ---------------- FC (128->2) + log_softmax, one wave per node ------------
__global__ __launch_bounds__(256) void fc_kernel(const float* __restrict__ x,
                                                 const float* __restrict__ Wfc,
                                                 const float* __restrict__ bfc,
                                                 float* __restrict__ out) {
    int gid = blockIdx.x * blockDim.x + threadIdx.x;
    int node = gid >> 6;
    int lane = gid & 63;
    if (node >= N_NODES) return;
    const float2 v = ((const float2*)(x + (size_t)node * 128))[lane];
    int k0 = lane * 2;
    float a0 = v.x * Wfc[k0 * 2 + 0] + v.y * Wfc[(k0 + 1) * 2 + 0];
    float a1 = v.x * Wfc[k0 * 2 + 1] + v.y * Wfc[(k0 + 1) * 2 + 1];
#pragma unroll
    for (int off = 32; off > 0; off >>= 1) {
        a0 += __shfl_down(a0, off);
        a1 += __shfl_down(a1, off);
    }
    if (lane == 0) {
        float l0 = a0 + bfc[0];
        float l1 = a1 + bfc[1];
        float m = fmaxf(l0, l1);
        float lse = m + logf(expf(l0 - m) + expf(l1 - m));
        out[(size_t)node * 2 + 0] = l0 - lse;
        out[(size_t)node * 2 + 1] = l1 - lse;
    }
}

extern "C" void kernel_launch(void* const* d_in, const int* in_sizes, int n_in,
                              void* d_out, int out_size, void* d_ws, size_t ws_size,
                              hipStream_t stream) {
    const float* x   = (const float*)d_in[0];
    const int*   ei  = (const int*)d_in[1];
    const float* W1  = (const float*)d_in[2];
    const float* b1  = (const float*)d_in[3];
    const float* W2  = (const float*)d_in[4];
    const float* b2  = (const float*)d_in[5];
    const float* Wfc = (const float*)d_in[6];
    const float* bfc = (const float*)d_in[7];
    float* out = (float*)d_out;

    const int* src = ei;
    const int* dst = ei + E_EDGES;

    // workspace layout (all 4-byte elements)
    int*   cnt    = (int*)d_ws;                          // N
    int*   rowptr = cnt + N_NODES;                       // N+1
    int*   cursor = rowptr + (N_NODES + 1);              // N
    int*   bsum   = cursor + N_NODES;                    // 128
    int*   ssrc   = bsum + 128;                          // E
    float* dinv   = (float*)(ssrc + E_EDGES);            // N
    float* hbuf   = dinv + N_NODES;                      // N*128
    float* x2buf  = hbuf + (size_t)N_NODES * FDIM;       // N*128

    const int NE_BLK = (E_EDGES + 255) / 256;
    const int NN_BLK = (N_NODES + 255) / 256;
    const int NODE_WAVE_BLK = (N_NODES * 64 + 255) / 256;

    // ---- build CSR (dst-sorted) + dinv ----
    hipMemsetAsync(cnt, 0, N_NODES * sizeof(int), stream);
    hipMemsetAsync(cursor, 0, N_NODES * sizeof(int), stream);
    hist_kernel<<<NE_BLK, 256, 0, stream>>>(dst, cnt);
    scan1<<<NSCAN_BLKS, 256, 0, stream>>>(cnt, rowptr, bsum);
    scan2<<<1, 128, 0, stream>>>(bsum);
    scan3<<<NN_BLK, 256, 0, stream>>>(rowptr, bsum, cnt, dinv);
    scatter_kernel<<<NE_BLK, 256, 0, stream>>>(src, dst, rowptr, cursor, ssrc);

    // ---- layer 1 ----
    gemm128<<<N_NODES / GEMM_ROWS, 128, 0, stream>>>(x, W1, hbuf);
    agg_kernel<<<NODE_WAVE_BLK, 256, 0, stream>>>(rowptr, ssrc, dinv, hbuf, b1, x2buf);

    // ---- layer 2 ----
    gemm128<<<N_NODES / GEMM_ROWS, 128, 0, stream>>>(x2buf, W2, hbuf);
    agg_kernel<<<NODE_WAVE_BLK, 256, 0, stream>>>(rowptr, ssrc, dinv, hbuf, b2, x2buf);

    // ---- FC + log_softmax ----
    fc_kernel<<<NODE_WAVE_BLK, 256, 0, stream>>>(x2buf, Wfc, bfc, out);
}

// Round 3
// 653.293 us; speedup vs baseline: 5.1550x; 1.7087x over previous
//
#include <hip/hip_runtime.h>
#include <math.h>

#define N_NODES 100000
#define FDIM 128
#define E_EDGES 1600000
#define NSCAN_BLKS ((N_NODES + 1023) / 1024)   // 98

// ---------------- in-degree histogram (int atomics) ----------------
__global__ __launch_bounds__(256) void hist_kernel(const int* __restrict__ dst,
                                                   int* __restrict__ cnt) {
    int e = blockIdx.x * blockDim.x + threadIdx.x;
    if (e < E_EDGES) atomicAdd(&cnt[dst[e]], 1);
}

// ---------------- 3-phase exclusive scan: cnt -> rowptr ----------------
__global__ __launch_bounds__(256) void scan1(const int* __restrict__ cnt,
                                             int* __restrict__ excl,
                                             int* __restrict__ bsum) {
    __shared__ int lds[256];
    const int b = blockIdx.x, t = threadIdx.x;
    const int base = b * 1024 + t * 4;
    int v[4];
#pragma unroll
    for (int q = 0; q < 4; ++q) {
        int i = base + q;
        v[q] = (i < N_NODES) ? cnt[i] : 0;
    }
    int tsum = v[0] + v[1] + v[2] + v[3];
    lds[t] = tsum;
    __syncthreads();
    for (int off = 1; off < 256; off <<= 1) {
        int x = lds[t];
        int y = (t >= off) ? lds[t - off] : 0;
        __syncthreads();
        lds[t] = x + y;
        __syncthreads();
    }
    int texcl = lds[t] - tsum;
    if (t == 255) bsum[b] = lds[t];
    int run = texcl;
#pragma unroll
    for (int q = 0; q < 4; ++q) {
        int i = base + q;
        if (i < N_NODES) excl[i] = run;
        run += v[q];
    }
}

__global__ __launch_bounds__(128) void scan2(int* __restrict__ bsum) {
    __shared__ int lds[128];
    const int t = threadIdx.x;
    int v = (t < NSCAN_BLKS) ? bsum[t] : 0;
    lds[t] = v;
    __syncthreads();
    for (int off = 1; off < 128; off <<= 1) {
        int x = lds[t];
        int y = (t >= off) ? lds[t - off] : 0;
        __syncthreads();
        lds[t] = x + y;
        __syncthreads();
    }
    if (t < NSCAN_BLKS) bsum[t] = lds[t] - v;   // exclusive
}

// add block offsets + compute dinv + close rowptr
__global__ __launch_bounds__(256) void scan3(int* __restrict__ rowptr,
                                             const int* __restrict__ bsum,
                                             const int* __restrict__ cnt,
                                             float* __restrict__ dinv) {
    int i = blockIdx.x * blockDim.x + threadIdx.x;
    if (i < N_NODES) {
        rowptr[i] += bsum[i >> 10];
        dinv[i] = rsqrtf((float)cnt[i] + 1.0f);
    }
    if (i == 0) rowptr[N_NODES] = E_EDGES;
}

// ---------------- scatter edges into dst-sorted order ----------------
__global__ __launch_bounds__(256) void scatter_kernel(const int* __restrict__ src,
                                                      const int* __restrict__ dst,
                                                      const int* __restrict__ rowptr,
                                                      int* __restrict__ cursor,
                                                      int* __restrict__ ssrc) {
    int e = blockIdx.x * blockDim.x + threadIdx.x;
    if (e >= E_EDGES) return;
    int d = dst[e];
    int p = rowptr[d] + atomicAdd(&cursor[d], 1);
    ssrc[p] = src[e];
}

// ---------------- register-tiled GEMM: H = X @ W ----------------
// block: 256 threads, 128 rows x 128 cols; thread: 8 rows x 8 cols.
// W in LDS (read-only after one load -> no barriers in K-loop).
// X streamed from global (16 lanes/wave share each row address -> L1 broadcast).
#define BM 128
#define TM 8
#define TN 8
__global__ __launch_bounds__(256) void gemm_rt(const float* __restrict__ X,
                                               const float* __restrict__ W,
                                               float* __restrict__ H) {
    __shared__ float Ws[128 * 128];
    const int tid = threadIdx.x;
    {   // cooperative W load: 4096 float4 / 256 threads = 16 each
        const float4* Wv = (const float4*)W;
        float4* Sv = (float4*)Ws;
#pragma unroll
        for (int i = 0; i < 16; ++i) Sv[i * 256 + tid] = Wv[i * 256 + tid];
    }
    __syncthreads();

    const int tc = (tid & 15) * TN;        // col base
    const int tr = (tid >> 4) * TM;        // row base within tile
    const long row0 = (long)blockIdx.x * BM + tr;

    const float* xp[TM];
    bool rowok[TM];
#pragma unroll
    for (int r = 0; r < TM; ++r) {
        long rr = row0 + r;
        rowok[r] = (rr < N_NODES);
        xp[r] = X + (rowok[r] ? rr : 0) * 128;
    }

    float acc[TM][TN];
#pragma unroll
    for (int r = 0; r < TM; ++r)
#pragma unroll
        for (int c = 0; c < TN; ++c) acc[r][c] = 0.f;

    float4 xa[TM], xb[TM];
#pragma unroll
    for (int r = 0; r < TM; ++r) xa[r] = ((const float4*)xp[r])[0];

    // K = 128 in steps of 4, 2-step unrolled with explicit double-buffer
    for (int k4 = 0; k4 < 32; k4 += 2) {
        // prefetch k4+1
#pragma unroll
        for (int r = 0; r < TM; ++r) xb[r] = ((const float4*)xp[r])[k4 + 1];
        // compute with xa (k = 4*k4 .. 4*k4+3)
#pragma unroll
        for (int kk = 0; kk < 4; ++kk) {
            const int k = k4 * 4 + kk;
            const float4 b0 = *((const float4*)(Ws + k * 128 + tc));
            const float4 b1 = *((const float4*)(Ws + k * 128 + tc + 4));
#pragma unroll
            for (int r = 0; r < TM; ++r) {
                const float xs = ((const float*)&xa[r])[kk];
                acc[r][0] = fmaf(xs, b0.x, acc[r][0]);
                acc[r][1] = fmaf(xs, b0.y, acc[r][1]);
                acc[r][2] = fmaf(xs, b0.z, acc[r][2]);
                acc[r][3] = fmaf(xs, b0.w, acc[r][3]);
                acc[r][4] = fmaf(xs, b1.x, acc[r][4]);
                acc[r][5] = fmaf(xs, b1.y, acc[r][5]);
                acc[r][6] = fmaf(xs, b1.z, acc[r][6]);
                acc[r][7] = fmaf(xs, b1.w, acc[r][7]);
            }
        }
        // prefetch k4+2 (guarded), compute with xb (k = 4*(k4+1) ..)
        if (k4 + 2 < 32) {
#pragma unroll
            for (int r = 0; r < TM; ++r) xa[r] = ((const float4*)xp[r])[k4 + 2];
        }
#pragma unroll
        for (int kk = 0; kk < 4; ++kk) {
            const int k = (k4 + 1) * 4 + kk;
            const float4 b0 = *((const float4*)(Ws + k * 128 + tc));
            const float4 b1 = *((const float4*)(Ws + k * 128 + tc + 4));
#pragma unroll
            for (int r = 0; r < TM; ++r) {
                const float xs = ((const float*)&xb[r])[kk];
                acc[r][0] = fmaf(xs, b0.x, acc[r][0]);
                acc[r][1] = fmaf(xs, b0.y, acc[r][1]);
                acc[r][2] = fmaf(xs, b0.z, acc[r][2]);
                acc[r][3] = fmaf(xs, b0.w, acc[r][3]);
                acc[r][4] = fmaf(xs, b1.x, acc[r][4]);
                acc[r][5] = fmaf(xs, b1.y, acc[r][5]);
                acc[r][6] = fmaf(xs, b1.z, acc[r][6]);
                acc[r][7] = fmaf(xs, b1.w, acc[r][7]);
            }
        }
    }

#pragma unroll
    for (int r = 0; r < TM; ++r) {
        if (rowok[r]) {
            float* hp = H + (row0 + r) * 128 + tc;
            *((float4*)hp) = make_float4(acc[r][0], acc[r][1], acc[r][2], acc[r][3]);
            *((float4*)(hp + 4)) = make_float4(acc[r][4], acc[r][5], acc[r][6], acc[r][7]);
        }
    }
}

// ------- fused gather-aggregate + self-loop + bias + ReLU: one wave/node ----
__global__ __launch_bounds__(256) void agg_kernel(const int* __restrict__ rowptr,
                                                  const int* __restrict__ ssrc,
                                                  const float* __restrict__ dinv,
                                                  const float* __restrict__ h,
                                                  const float* __restrict__ bias,
                                                  float* __restrict__ out) {
    int gid = blockIdx.x * blockDim.x + threadIdx.x;
    int node = gid >> 6;
    int lane = gid & 63;
    if (node >= N_NODES) return;
    float dd = dinv[node];
    float2 v = ((const float2*)(h + (size_t)node * 128))[lane];
    float sc = dd * dd;
    float accx = v.x * sc, accy = v.y * sc;
    int j = rowptr[node];
    const int end = rowptr[node + 1];
    for (; j + 3 < end; j += 4) {
        int s0 = ssrc[j], s1 = ssrc[j + 1], s2 = ssrc[j + 2], s3 = ssrc[j + 3];
        float n0 = dinv[s0] * dd, n1 = dinv[s1] * dd;
        float n2 = dinv[s2] * dd, n3 = dinv[s3] * dd;
        float2 v0 = ((const float2*)(h + (size_t)s0 * 128))[lane];
        float2 v1 = ((const float2*)(h + (size_t)s1 * 128))[lane];
        float2 v2 = ((const float2*)(h + (size_t)s2 * 128))[lane];
        float2 v3 = ((const float2*)(h + (size_t)s3 * 128))[lane];
        accx += v0.x * n0 + v1.x * n1 + v2.x * n2 + v3.x * n3;
        accy += v0.y * n0 + v1.y * n1 + v2.y * n2 + v3.y * n3;
    }
    for (; j < end; ++j) {
        int s0 = ssrc[j];
        float n0 = dinv[s0] * dd;
        float2 v0 = ((const float2*)(h + (size_t)s0 * 128))[lane];
        accx += v0.x * n0;
        accy += v0.y * n0;
    }
    float2 b = ((const float2*)bias)[lane];
    accx = fmaxf(accx + b.x, 0.f);
    accy = fmaxf(accy + b.y, 0.f);
    ((float2*)(out + (size_t)node * 128))[lane] = make_float2(accx, accy);
}

// ------- layer-2 agg fused with FC(128->2) + log_softmax ----
__global__ __launch_bounds__(256) void agg_fc_kernel(const int* __restrict__ rowptr,
                                                     const int* __restrict__ ssrc,
                                                     const float* __restrict__ dinv,
                                                     const float* __restrict__ h,
                                                     const float* __restrict__ bias,
                                                     const float* __restrict__ Wfc,
                                                     const float* __restrict__ bfc,
                                                     float* __restrict__ out) {
    int gid = blockIdx.x * blockDim.x + threadIdx.x;
    int node = gid >> 6;
    int lane = gid & 63;
    if (node >= N_NODES) return;
    float dd = dinv[node];
    float2 v = ((const float2*)(h + (size_t)node * 128))[lane];
    float sc = dd * dd;
    float accx = v.x * sc, accy = v.y * sc;
    int j = rowptr[node];
    const int end = rowptr[node + 1];
    for (; j + 3 < end; j += 4) {
        int s0 = ssrc[j], s1 = ssrc[j + 1], s2 = ssrc[j + 2], s3 = ssrc[j + 3];
        float n0 = dinv[s0] * dd, n1 = dinv[s1] * dd;
        float n2 = dinv[s2] * dd, n3 = dinv[s3] * dd;
        float2 v0 = ((const float2*)(h + (size_t)s0 * 128))[lane];
        float2 v1 = ((const float2*)(h + (size_t)s1 * 128))[lane];
        float2 v2 = ((const float2*)(h + (size_t)s2 * 128))[lane];
        float2 v3 = ((const float2*)(h + (size_t)s3 * 128))[lane];
        accx += v0.x * n0 + v1.x * n1 + v2.x * n2 + v3.x * n3;
        accy += v0.y * n0 + v1.y * n1 + v2.y * n2 + v3.y * n3;
    }
    for (; j < end; ++j) {
        int s0 = ssrc[j];
        float n0 = dinv[s0] * dd;
        float2 v0 = ((const float2*)(h + (size_t)s0 * 128))[lane];
        accx += v0.x * n0;
        accy += v0.y * n0;
    }
    float2 b = ((const float2*)bias)[lane];
    accx = fmaxf(accx + b.x, 0.f);
    accy = fmaxf(accy + b.y, 0.f);
    // FC: lane covers k = 2*lane, 2*lane+1 ; Wfc is [128][2] row-major
    int k0 = lane * 2;
    float a0 = accx * Wfc[k0 * 2 + 0] + accy * Wfc[(k0 + 1) * 2 + 0];
    float a1 = accx * Wfc[k0 * 2 + 1] + accy * Wfc[(k0 + 1) * 2 + 1];
#pragma unroll
    for (int off = 32; off > 0; off >>= 1) {
        a0 += __shfl_down(a0, off);
        a1 += __shfl_down(a1, off);
    }
    if (lane == 0) {
        float l0 = a0 + bfc[0];
        float l1 = a1 + bfc[1];
        float m = fmaxf(l0, l1);
        float lse = m + logf(expf(l0 - m) + expf(l1 - m));
        out[(size_t)node * 2 + 0] = l0 - lse;
        out[(size_t)node * 2 + 1] = l1 - lse;
    }
}

extern "C" void kernel_launch(void* const* d_in, const int* in_sizes, int n_in,
                              void* d_out, int out_size, void* d_ws, size_t ws_size,
                              hipStream_t stream) {
    const float* x   = (const float*)d_in[0];
    const int*   ei  = (const int*)d_in[1];
    const float* W1  = (const float*)d_in[2];
    const float* b1  = (const float*)d_in[3];
    const float* W2  = (const float*)d_in[4];
    const float* b2  = (const float*)d_in[5];
    const float* Wfc = (const float*)d_in[6];
    const float* bfc = (const float*)d_in[7];
    float* out = (float*)d_out;

    const int* src = ei;
    const int* dst = ei + E_EDGES;

    // workspace layout (all 4-byte elements)
    int*   cnt    = (int*)d_ws;                          // N
    int*   rowptr = cnt + N_NODES;                       // N+1
    int*   cursor = rowptr + (N_NODES + 1);              // N
    int*   bsum   = cursor + N_NODES;                    // 128
    int*   ssrc   = bsum + 128;                          // E
    float* dinv   = (float*)(ssrc + E_EDGES);            // N
    float* hbuf   = dinv + N_NODES;                      // N*128
    float* x2buf  = hbuf + (size_t)N_NODES * FDIM;       // N*128

    const int NE_BLK = (E_EDGES + 255) / 256;
    const int NN_BLK = (N_NODES + 255) / 256;
    const int NODE_WAVE_BLK = (N_NODES * 64 + 255) / 256;
    const int GEMM_BLK = (N_NODES + BM - 1) / BM;

    // ---- build CSR (dst-sorted) + dinv ----
    hipMemsetAsync(cnt, 0, N_NODES * sizeof(int), stream);
    hipMemsetAsync(cursor, 0, N_NODES * sizeof(int), stream);
    hist_kernel<<<NE_BLK, 256, 0, stream>>>(dst, cnt);
    scan1<<<NSCAN_BLKS, 256, 0, stream>>>(cnt, rowptr, bsum);
    scan2<<<1, 128, 0, stream>>>(bsum);
    scan3<<<NN_BLK, 256, 0, stream>>>(rowptr, bsum, cnt, dinv);
    scatter_kernel<<<NE_BLK, 256, 0, stream>>>(src, dst, rowptr, cursor, ssrc);

    // ---- layer 1 ----
    gemm_rt<<<GEMM_BLK, 256, 0, stream>>>(x, W1, hbuf);
    agg_kernel<<<NODE_WAVE_BLK, 256, 0, stream>>>(rowptr, ssrc, dinv, hbuf, b1, x2buf);

    // ---- layer 2 (agg fused with FC + log_softmax) ----
    gemm_rt<<<GEMM_BLK, 256, 0, stream>>>(x2buf, W2, hbuf);
    agg_fc_kernel<<<NODE_WAVE_BLK, 256, 0, stream>>>(rowptr, ssrc, dinv, hbuf, b2,
                                                     Wfc, bfc, out);
}

// Round 4
// 536.843 us; speedup vs baseline: 6.2732x; 1.2169x over previous
//
#include <hip/hip_runtime.h>
#include <math.h>

#define N_NODES 100000
#define FDIM 128
#define E_EDGES 1600000
#define NSCAN_BLKS ((N_NODES + 1023) / 1024)   // 98

typedef unsigned short bf16_t;

__device__ inline bf16_t f2bf(float f) {
    unsigned int u = __float_as_uint(f);
    return (bf16_t)((u + 0x7fffu + ((u >> 16) & 1u)) >> 16);   // RNE
}
// unpack uint (2 packed bf16) -> float2 (x = low element = even col)
__device__ inline float2 bfpair(unsigned int u) {
    return make_float2(__uint_as_float(u << 16), __uint_as_float(u & 0xffff0000u));
}

// ---------------- in-degree histogram (int atomics) ----------------
__global__ __launch_bounds__(256) void hist_kernel(const int* __restrict__ dst,
                                                   int* __restrict__ cnt) {
    int e = blockIdx.x * blockDim.x + threadIdx.x;
    if (e < E_EDGES) atomicAdd(&cnt[dst[e]], 1);
}

// ---------------- 3-phase exclusive scan: cnt -> rowptr ----------------
__global__ __launch_bounds__(256) void scan1(const int* __restrict__ cnt,
                                             int* __restrict__ excl,
                                             int* __restrict__ bsum) {
    __shared__ int lds[256];
    const int b = blockIdx.x, t = threadIdx.x;
    const int base = b * 1024 + t * 4;
    int v[4];
#pragma unroll
    for (int q = 0; q < 4; ++q) {
        int i = base + q;
        v[q] = (i < N_NODES) ? cnt[i] : 0;
    }
    int tsum = v[0] + v[1] + v[2] + v[3];
    lds[t] = tsum;
    __syncthreads();
    for (int off = 1; off < 256; off <<= 1) {
        int x = lds[t];
        int y = (t >= off) ? lds[t - off] : 0;
        __syncthreads();
        lds[t] = x + y;
        __syncthreads();
    }
    int texcl = lds[t] - tsum;
    if (t == 255) bsum[b] = lds[t];
    int run = texcl;
#pragma unroll
    for (int q = 0; q < 4; ++q) {
        int i = base + q;
        if (i < N_NODES) excl[i] = run;
        run += v[q];
    }
}

__global__ __launch_bounds__(128) void scan2(int* __restrict__ bsum) {
    __shared__ int lds[128];
    const int t = threadIdx.x;
    int v = (t < NSCAN_BLKS) ? bsum[t] : 0;
    lds[t] = v;
    __syncthreads();
    for (int off = 1; off < 128; off <<= 1) {
        int x = lds[t];
        int y = (t >= off) ? lds[t - off] : 0;
        __syncthreads();
        lds[t] = x + y;
        __syncthreads();
    }
    if (t < NSCAN_BLKS) bsum[t] = lds[t] - v;   // exclusive
}

// add block offsets + compute dinv + close rowptr
__global__ __launch_bounds__(256) void scan3(int* __restrict__ rowptr,
                                             const int* __restrict__ bsum,
                                             const int* __restrict__ cnt,
                                             float* __restrict__ dinv) {
    int i = blockIdx.x * blockDim.x + threadIdx.x;
    if (i < N_NODES) {
        rowptr[i] += bsum[i >> 10];
        dinv[i] = rsqrtf((float)cnt[i] + 1.0f);
    }
    if (i == 0) rowptr[N_NODES] = E_EDGES;
}

// ---------------- scatter edges into dst-sorted order ----------------
__global__ __launch_bounds__(256) void scatter_kernel(const int* __restrict__ src,
                                                      const int* __restrict__ dst,
                                                      const int* __restrict__ rowptr,
                                                      int* __restrict__ cursor,
                                                      int* __restrict__ ssrc) {
    int e = blockIdx.x * blockDim.x + threadIdx.x;
    if (e >= E_EDGES) return;
    int d = dst[e];
    int p = rowptr[d] + atomicAdd(&cursor[d], 1);
    ssrc[p] = src[e];
}

// ---------------- register-tiled GEMM: H(bf16) = X(f32) @ W(f32) ----------
// block: 256 threads, 128 rows x 128 cols; thread: 8 rows x 8 cols.
#define BM 128
#define TM 8
#define TN 8
__global__ __launch_bounds__(256) void gemm_rt(const float* __restrict__ X,
                                               const float* __restrict__ W,
                                               bf16_t* __restrict__ H) {
    __shared__ float Ws[128 * 128];
    const int tid = threadIdx.x;
    {   // cooperative W load: 4096 float4 / 256 threads = 16 each
        const float4* Wv = (const float4*)W;
        float4* Sv = (float4*)Ws;
#pragma unroll
        for (int i = 0; i < 16; ++i) Sv[i * 256 + tid] = Wv[i * 256 + tid];
    }
    __syncthreads();

    const int tc = (tid & 15) * TN;        // col base
    const int tr = (tid >> 4) * TM;        // row base within tile
    const long row0 = (long)blockIdx.x * BM + tr;

    const float* xp[TM];
    bool rowok[TM];
#pragma unroll
    for (int r = 0; r < TM; ++r) {
        long rr = row0 + r;
        rowok[r] = (rr < N_NODES);
        xp[r] = X + (rowok[r] ? rr : 0) * 128;
    }

    float acc[TM][TN];
#pragma unroll
    for (int r = 0; r < TM; ++r)
#pragma unroll
        for (int c = 0; c < TN; ++c) acc[r][c] = 0.f;

    float4 xa[TM], xb[TM];
#pragma unroll
    for (int r = 0; r < TM; ++r) xa[r] = ((const float4*)xp[r])[0];

    for (int k4 = 0; k4 < 32; k4 += 2) {
#pragma unroll
        for (int r = 0; r < TM; ++r) xb[r] = ((const float4*)xp[r])[k4 + 1];
#pragma unroll
        for (int kk = 0; kk < 4; ++kk) {
            const int k = k4 * 4 + kk;
            const float4 b0 = *((const float4*)(Ws + k * 128 + tc));
            const float4 b1 = *((const float4*)(Ws + k * 128 + tc + 4));
#pragma unroll
            for (int r = 0; r < TM; ++r) {
                const float xs = ((const float*)&xa[r])[kk];
                acc[r][0] = fmaf(xs, b0.x, acc[r][0]);
                acc[r][1] = fmaf(xs, b0.y, acc[r][1]);
                acc[r][2] = fmaf(xs, b0.z, acc[r][2]);
                acc[r][3] = fmaf(xs, b0.w, acc[r][3]);
                acc[r][4] = fmaf(xs, b1.x, acc[r][4]);
                acc[r][5] = fmaf(xs, b1.y, acc[r][5]);
                acc[r][6] = fmaf(xs, b1.z, acc[r][6]);
                acc[r][7] = fmaf(xs, b1.w, acc[r][7]);
            }
        }
        if (k4 + 2 < 32) {
#pragma unroll
            for (int r = 0; r < TM; ++r) xa[r] = ((const float4*)xp[r])[k4 + 2];
        }
#pragma unroll
        for (int kk = 0; kk < 4; ++kk) {
            const int k = (k4 + 1) * 4 + kk;
            const float4 b0 = *((const float4*)(Ws + k * 128 + tc));
            const float4 b1 = *((const float4*)(Ws + k * 128 + tc + 4));
#pragma unroll
            for (int r = 0; r < TM; ++r) {
                const float xs = ((const float*)&xb[r])[kk];
                acc[r][0] = fmaf(xs, b0.x, acc[r][0]);
                acc[r][1] = fmaf(xs, b0.y, acc[r][1]);
                acc[r][2] = fmaf(xs, b0.z, acc[r][2]);
                acc[r][3] = fmaf(xs, b0.w, acc[r][3]);
                acc[r][4] = fmaf(xs, b1.x, acc[r][4]);
                acc[r][5] = fmaf(xs, b1.y, acc[r][5]);
                acc[r][6] = fmaf(xs, b1.z, acc[r][6]);
                acc[r][7] = fmaf(xs, b1.w, acc[r][7]);
            }
        }
    }

#pragma unroll
    for (int r = 0; r < TM; ++r) {
        if (rowok[r]) {
            uint4 o;
            o.x = (unsigned)f2bf(acc[r][0]) | ((unsigned)f2bf(acc[r][1]) << 16);
            o.y = (unsigned)f2bf(acc[r][2]) | ((unsigned)f2bf(acc[r][3]) << 16);
            o.z = (unsigned)f2bf(acc[r][4]) | ((unsigned)f2bf(acc[r][5]) << 16);
            o.w = (unsigned)f2bf(acc[r][6]) | ((unsigned)f2bf(acc[r][7]) << 16);
            *((uint4*)(H + (size_t)(row0 + r) * 128 + tc)) = o;
        }
    }
}

// ------- fused gather-aggregate + self-loop + bias + ReLU: one wave/node ----
// h is bf16 [N][128]; lane reads one packed uint (cols 2*lane, 2*lane+1).
__global__ __launch_bounds__(256) void agg_kernel(const int* __restrict__ rowptr,
                                                  const int* __restrict__ ssrc,
                                                  const float* __restrict__ dinv,
                                                  const bf16_t* __restrict__ h,
                                                  const float* __restrict__ bias,
                                                  float* __restrict__ out) {
    int gid = blockIdx.x * blockDim.x + threadIdx.x;
    int node = gid >> 6;
    int lane = gid & 63;
    if (node >= N_NODES) return;
    float dd = dinv[node];
    float2 v = bfpair(((const unsigned*)(h + (size_t)node * 128))[lane]);
    float sc = dd * dd;
    float accx = v.x * sc, accy = v.y * sc;
    int j = rowptr[node];
    const int end = rowptr[node + 1];
    for (; j + 3 < end; j += 4) {
        int s0 = ssrc[j], s1 = ssrc[j + 1], s2 = ssrc[j + 2], s3 = ssrc[j + 3];
        float n0 = dinv[s0] * dd, n1 = dinv[s1] * dd;
        float n2 = dinv[s2] * dd, n3 = dinv[s3] * dd;
        float2 v0 = bfpair(((const unsigned*)(h + (size_t)s0 * 128))[lane]);
        float2 v1 = bfpair(((const unsigned*)(h + (size_t)s1 * 128))[lane]);
        float2 v2 = bfpair(((const unsigned*)(h + (size_t)s2 * 128))[lane]);
        float2 v3 = bfpair(((const unsigned*)(h + (size_t)s3 * 128))[lane]);
        accx += v0.x * n0 + v1.x * n1 + v2.x * n2 + v3.x * n3;
        accy += v0.y * n0 + v1.y * n1 + v2.y * n2 + v3.y * n3;
    }
    for (; j < end; ++j) {
        int s0 = ssrc[j];
        float n0 = dinv[s0] * dd;
        float2 v0 = bfpair(((const unsigned*)(h + (size_t)s0 * 128))[lane]);
        accx += v0.x * n0;
        accy += v0.y * n0;
    }
    float2 b = ((const float2*)bias)[lane];
    accx = fmaxf(accx + b.x, 0.f);
    accy = fmaxf(accy + b.y, 0.f);
    ((float2*)(out + (size_t)node * 128))[lane] = make_float2(accx, accy);
}

// ------- layer-2 agg fused with FC(128->2) + log_softmax ----
__global__ __launch_bounds__(256) void agg_fc_kernel(const int* __restrict__ rowptr,
                                                     const int* __restrict__ ssrc,
                                                     const float* __restrict__ dinv,
                                                     const bf16_t* __restrict__ h,
                                                     const float* __restrict__ bias,
                                                     const float* __restrict__ Wfc,
                                                     const float* __restrict__ bfc,
                                                     float* __restrict__ out) {
    int gid = blockIdx.x * blockDim.x + threadIdx.x;
    int node = gid >> 6;
    int lane = gid & 63;
    if (node >= N_NODES) return;
    float dd = dinv[node];
    float2 v = bfpair(((const unsigned*)(h + (size_t)node * 128))[lane]);
    float sc = dd * dd;
    float accx = v.x * sc, accy = v.y * sc;
    int j = rowptr[node];
    const int end = rowptr[node + 1];
    for (; j + 3 < end; j += 4) {
        int s0 = ssrc[j], s1 = ssrc[j + 1], s2 = ssrc[j + 2], s3 = ssrc[j + 3];
        float n0 = dinv[s0] * dd, n1 = dinv[s1] * dd;
        float n2 = dinv[s2] * dd, n3 = dinv[s3] * dd;
        float2 v0 = bfpair(((const unsigned*)(h + (size_t)s0 * 128))[lane]);
        float2 v1 = bfpair(((const unsigned*)(h + (size_t)s1 * 128))[lane]);
        float2 v2 = bfpair(((const unsigned*)(h + (size_t)s2 * 128))[lane]);
        float2 v3 = bfpair(((const unsigned*)(h + (size_t)s3 * 128))[lane]);
        accx += v0.x * n0 + v1.x * n1 + v2.x * n2 + v3.x * n3;
        accy += v0.y * n0 + v1.y * n1 + v2.y * n2 + v3.y * n3;
    }
    for (; j < end; ++j) {
        int s0 = ssrc[j];
        float n0 = dinv[s0] * dd;
        float2 v0 = bfpair(((const unsigned*)(h + (size_t)s0 * 128))[lane]);
        accx += v0.x * n0;
        accy += v0.y * n0;
    }
    float2 b = ((const float2*)bias)[lane];
    accx = fmaxf(accx + b.x, 0.f);
    accy = fmaxf(accy + b.y, 0.f);
    // FC: lane covers k = 2*lane, 2*lane+1 ; Wfc is [128][2] row-major
    int k0 = lane * 2;
    float a0 = accx * Wfc[k0 * 2 + 0] + accy * Wfc[(k0 + 1) * 2 + 0];
    float a1 = accx * Wfc[k0 * 2 + 1] + accy * Wfc[(k0 + 1) * 2 + 1];
#pragma unroll
    for (int off = 32; off > 0; off >>= 1) {
        a0 += __shfl_down(a0, off);
        a1 += __shfl_down(a1, off);
    }
    if (lane == 0) {
        float l0 = a0 + bfc[0];
        float l1 = a1 + bfc[1];
        float m = fmaxf(l0, l1);
        float lse = m + logf(expf(l0 - m) + expf(l1 - m));
        out[(size_t)node * 2 + 0] = l0 - lse;
        out[(size_t)node * 2 + 1] = l1 - lse;
    }
}

extern "C" void kernel_launch(void* const* d_in, const int* in_sizes, int n_in,
                              void* d_out, int out_size, void* d_ws, size_t ws_size,
                              hipStream_t stream) {
    const float* x   = (const float*)d_in[0];
    const int*   ei  = (const int*)d_in[1];
    const float* W1  = (const float*)d_in[2];
    const float* b1  = (const float*)d_in[3];
    const float* W2  = (const float*)d_in[4];
    const float* b2  = (const float*)d_in[5];
    const float* Wfc = (const float*)d_in[6];
    const float* bfc = (const float*)d_in[7];
    float* out = (float*)d_out;

    const int* src = ei;
    const int* dst = ei + E_EDGES;

    // workspace: 256B-aligned carve (uint4 stores need 16B alignment)
    char* wp = (char*)d_ws;
    auto carve = [&](size_t bytes) -> char* {
        char* p = wp;
        wp += (bytes + 255) & ~(size_t)255;
        return p;
    };
    int*    cnt    = (int*)carve(N_NODES * 4);
    int*    rowptr = (int*)carve((N_NODES + 1) * 4);
    int*    cursor = (int*)carve(N_NODES * 4);
    int*    bsum   = (int*)carve(128 * 4);
    int*    ssrc   = (int*)carve((size_t)E_EDGES * 4);
    float*  dinv   = (float*)carve(N_NODES * 4);
    bf16_t* hbuf   = (bf16_t*)carve((size_t)N_NODES * FDIM * 2);
    float*  x2buf  = (float*)carve((size_t)N_NODES * FDIM * 4);

    const int NE_BLK = (E_EDGES + 255) / 256;
    const int NN_BLK = (N_NODES + 255) / 256;
    const int NODE_WAVE_BLK = (N_NODES * 64 + 255) / 256;
    const int GEMM_BLK = (N_NODES + BM - 1) / BM;

    // ---- build CSR (dst-sorted) + dinv ----
    hipMemsetAsync(cnt, 0, N_NODES * sizeof(int), stream);
    hipMemsetAsync(cursor, 0, N_NODES * sizeof(int), stream);
    hist_kernel<<<NE_BLK, 256, 0, stream>>>(dst, cnt);
    scan1<<<NSCAN_BLKS, 256, 0, stream>>>(cnt, rowptr, bsum);
    scan2<<<1, 128, 0, stream>>>(bsum);
    scan3<<<NN_BLK, 256, 0, stream>>>(rowptr, bsum, cnt, dinv);
    scatter_kernel<<<NE_BLK, 256, 0, stream>>>(src, dst, rowptr, cursor, ssrc);

    // ---- layer 1 ----
    gemm_rt<<<GEMM_BLK, 256, 0, stream>>>(x, W1, hbuf);
    agg_kernel<<<NODE_WAVE_BLK, 256, 0, stream>>>(rowptr, ssrc, dinv, hbuf, b1, x2buf);

    // ---- layer 2 (agg fused with FC + log_softmax) ----
    gemm_rt<<<GEMM_BLK, 256, 0, stream>>>(x2buf, W2, hbuf);
    agg_fc_kernel<<<NODE_WAVE_BLK, 256, 0, stream>>>(rowptr, ssrc, dinv, hbuf, b2,
                                                     Wfc, bfc, out);
}

// Round 5
// 461.934 us; speedup vs baseline: 7.2905x; 1.1622x over previous
//
#include <hip/hip_runtime.h>
#include <math.h>

#define N_NODES 100000
#define FDIM 128
#define E_EDGES 1600000
#define NSCAN_BLKS ((N_NODES + 1023) / 1024)   // 98
#define NPASS 8
#define PASS_NODES 12500                        // N_NODES / NPASS exactly

typedef unsigned short bf16_t;
typedef __attribute__((ext_vector_type(8))) short short8;
typedef __attribute__((ext_vector_type(4))) float f32x4;

__device__ inline bf16_t f2bf(float f) {
    unsigned int u = __float_as_uint(f);
    return (bf16_t)((u + 0x7fffu + ((u >> 16) & 1u)) >> 16);   // RNE
}
// unpack uint (2 packed bf16) -> float2 (x = low element = even col)
__device__ inline float2 bfpair(unsigned int u) {
    return make_float2(__uint_as_float(u << 16), __uint_as_float(u & 0xffff0000u));
}

// ---------------- in-degree histogram, range-partitioned (XCD-local) -------
__global__ __launch_bounds__(256) void hist_kernel(const int* __restrict__ dst,
                                                   int* __restrict__ cnt) {
    int pass = blockIdx.x & (NPASS - 1);
    int e = (blockIdx.x >> 3) * 256 + threadIdx.x;
    if (e >= E_EDGES) return;
    int d = dst[e];
    if ((unsigned)(d - pass * PASS_NODES) < (unsigned)PASS_NODES)
        atomicAdd(&cnt[d], 1);
}

// ---------------- 3-phase exclusive scan: cnt -> rowptr ----------------
__global__ __launch_bounds__(256) void scan1(const int* __restrict__ cnt,
                                             int* __restrict__ excl,
                                             int* __restrict__ bsum) {
    __shared__ int lds[256];
    const int b = blockIdx.x, t = threadIdx.x;
    const int base = b * 1024 + t * 4;
    int v[4];
#pragma unroll
    for (int q = 0; q < 4; ++q) {
        int i = base + q;
        v[q] = (i < N_NODES) ? cnt[i] : 0;
    }
    int tsum = v[0] + v[1] + v[2] + v[3];
    lds[t] = tsum;
    __syncthreads();
    for (int off = 1; off < 256; off <<= 1) {
        int x = lds[t];
        int y = (t >= off) ? lds[t - off] : 0;
        __syncthreads();
        lds[t] = x + y;
        __syncthreads();
    }
    int texcl = lds[t] - tsum;
    if (t == 255) bsum[b] = lds[t];
    int run = texcl;
#pragma unroll
    for (int q = 0; q < 4; ++q) {
        int i = base + q;
        if (i < N_NODES) excl[i] = run;
        run += v[q];
    }
}

__global__ __launch_bounds__(128) void scan2(int* __restrict__ bsum) {
    __shared__ int lds[128];
    const int t = threadIdx.x;
    int v = (t < NSCAN_BLKS) ? bsum[t] : 0;
    lds[t] = v;
    __syncthreads();
    for (int off = 1; off < 128; off <<= 1) {
        int x = lds[t];
        int y = (t >= off) ? lds[t - off] : 0;
        __syncthreads();
        lds[t] = x + y;
        __syncthreads();
    }
    if (t < NSCAN_BLKS) bsum[t] = lds[t] - v;   // exclusive
}

// add block offsets + compute dinv + close rowptr
__global__ __launch_bounds__(256) void scan3(int* __restrict__ rowptr,
                                             const int* __restrict__ bsum,
                                             const int* __restrict__ cnt,
                                             float* __restrict__ dinv) {
    int i = blockIdx.x * blockDim.x + threadIdx.x;
    if (i < N_NODES) {
        rowptr[i] += bsum[i >> 10];
        dinv[i] = rsqrtf((float)cnt[i] + 1.0f);
    }
    if (i == 0) rowptr[N_NODES] = E_EDGES;
}

// ---------------- scatter edges, range-partitioned (XCD-local writes) ------
__global__ __launch_bounds__(256) void scatter_kernel(const int* __restrict__ src,
                                                      const int* __restrict__ dst,
                                                      const int* __restrict__ rowptr,
                                                      int* __restrict__ cursor,
                                                      int* __restrict__ ssrc) {
    int pass = blockIdx.x & (NPASS - 1);
    int e = (blockIdx.x >> 3) * 256 + threadIdx.x;
    if (e >= E_EDGES) return;
    int d = dst[e];
    if ((unsigned)(d - pass * PASS_NODES) < (unsigned)PASS_NODES) {
        int p = rowptr[d] + atomicAdd(&cursor[d], 1);
        ssrc[p] = src[e];
    }
}

// ---------------- W [k][c] fp32 -> Wt [c][k] bf16 (B^T layout) ------------
__global__ __launch_bounds__(256) void wcvt_kernel(const float* __restrict__ W,
                                                   bf16_t* __restrict__ Wt) {
    int idx = blockIdx.x * 256 + threadIdx.x;   // over 16384
    int k = idx >> 7, c = idx & 127;
    Wt[c * 128 + k] = f2bf(W[idx]);
}

// ---------------- MFMA GEMM: H(bf16) = A @ Wt^T ----------------
// Block = 4 waves; wave w computes rows [row0, row0+16) x all 128 cols.
// Per k-step (K=32): A-frag from global (row = lane&15, k contiguous),
// 8 B-frags from global Wt[c][k] (c = ct*16 + lane&15, k contiguous),
// 8 x mfma_f32_16x16x32_bf16. C/D: col = lane&15, row = (lane>>4)*4 + reg.
template <bool A_IS_F32>
__global__ __launch_bounds__(256) void gemm_mfma(const void* __restrict__ Aptr,
                                                 const bf16_t* __restrict__ Wt,
                                                 bf16_t* __restrict__ H) {
    const int tid = threadIdx.x;
    const int wave = tid >> 6;
    const int l = tid & 63;
    const int r = l & 15;          // A row / B col within tile
    const int g = l >> 4;          // k-group (0..3)
    const int row0 = (blockIdx.x * 4 + wave) * 16;
    const int arow = min(row0 + r, N_NODES - 1);

    f32x4 acc[8];
#pragma unroll
    for (int ct = 0; ct < 8; ++ct) acc[ct] = (f32x4){0.f, 0.f, 0.f, 0.f};

#pragma unroll
    for (int ks = 0; ks < 4; ++ks) {
        const int kbase = ks * 32 + g * 8;
        short8 a;
        if constexpr (A_IS_F32) {
            const float* X = (const float*)Aptr;
            const float4 x0 = *((const float4*)(X + (size_t)arow * 128 + kbase));
            const float4 x1 = *((const float4*)(X + (size_t)arow * 128 + kbase + 4));
            a[0] = (short)f2bf(x0.x); a[1] = (short)f2bf(x0.y);
            a[2] = (short)f2bf(x0.z); a[3] = (short)f2bf(x0.w);
            a[4] = (short)f2bf(x1.x); a[5] = (short)f2bf(x1.y);
            a[6] = (short)f2bf(x1.z); a[7] = (short)f2bf(x1.w);
        } else {
            const bf16_t* X = (const bf16_t*)Aptr;
            a = *((const short8*)(X + (size_t)arow * 128 + kbase));
        }
#pragma unroll
        for (int ct = 0; ct < 8; ++ct) {
            short8 b = *((const short8*)(Wt + (ct * 16 + r) * 128 + kbase));
            acc[ct] = __builtin_amdgcn_mfma_f32_16x16x32_bf16(a, b, acc[ct], 0, 0, 0);
        }
    }

    // epilogue: D[row=(l>>4)*4+j][col=ct*16+r]
#pragma unroll
    for (int j = 0; j < 4; ++j) {
        const int row = row0 + g * 4 + j;
        if (row < N_NODES) {
            bf16_t* hp = H + (size_t)row * 128 + r;
#pragma unroll
            for (int ct = 0; ct < 8; ++ct) hp[ct * 16] = f2bf(acc[ct][j]);
        }
    }
}

// ------- fused gather-aggregate + self-loop + bias + ReLU -> bf16 out ------
__global__ __launch_bounds__(256) void agg_kernel(const int* __restrict__ rowptr,
                                                  const int* __restrict__ ssrc,
                                                  const float* __restrict__ dinv,
                                                  const bf16_t* __restrict__ h,
                                                  const float* __restrict__ bias,
                                                  bf16_t* __restrict__ out) {
    int gid = blockIdx.x * blockDim.x + threadIdx.x;
    int node = gid >> 6;
    int lane = gid & 63;
    if (node >= N_NODES) return;
    float dd = dinv[node];
    float2 v = bfpair(((const unsigned*)(h + (size_t)node * 128))[lane]);
    float sc = dd * dd;
    float accx = v.x * sc, accy = v.y * sc;
    int j = rowptr[node];
    const int end = rowptr[node + 1];
    for (; j + 3 < end; j += 4) {
        int s0 = ssrc[j], s1 = ssrc[j + 1], s2 = ssrc[j + 2], s3 = ssrc[j + 3];
        float n0 = dinv[s0] * dd, n1 = dinv[s1] * dd;
        float n2 = dinv[s2] * dd, n3 = dinv[s3] * dd;
        float2 v0 = bfpair(((const unsigned*)(h + (size_t)s0 * 128))[lane]);
        float2 v1 = bfpair(((const unsigned*)(h + (size_t)s1 * 128))[lane]);
        float2 v2 = bfpair(((const unsigned*)(h + (size_t)s2 * 128))[lane]);
        float2 v3 = bfpair(((const unsigned*)(h + (size_t)s3 * 128))[lane]);
        accx += v0.x * n0 + v1.x * n1 + v2.x * n2 + v3.x * n3;
        accy += v0.y * n0 + v1.y * n1 + v2.y * n2 + v3.y * n3;
    }
    for (; j < end; ++j) {
        int s0 = ssrc[j];
        float n0 = dinv[s0] * dd;
        float2 v0 = bfpair(((const unsigned*)(h + (size_t)s0 * 128))[lane]);
        accx += v0.x * n0;
        accy += v0.y * n0;
    }
    float2 b = ((const float2*)bias)[lane];
    accx = fmaxf(accx + b.x, 0.f);
    accy = fmaxf(accy + b.y, 0.f);
    unsigned o = (unsigned)f2bf(accx) | ((unsigned)f2bf(accy) << 16);
    ((unsigned*)(out + (size_t)node * 128))[lane] = o;
}

// ------- layer-2 agg fused with FC(128->2) + log_softmax ----
__global__ __launch_bounds__(256) void agg_fc_kernel(const int* __restrict__ rowptr,
                                                     const int* __restrict__ ssrc,
                                                     const float* __restrict__ dinv,
                                                     const bf16_t* __restrict__ h,
                                                     const float* __restrict__ bias,
                                                     const float* __restrict__ Wfc,
                                                     const float* __restrict__ bfc,
                                                     float* __restrict__ out) {
    int gid = blockIdx.x * blockDim.x + threadIdx.x;
    int node = gid >> 6;
    int lane = gid & 63;
    if (node >= N_NODES) return;
    float dd = dinv[node];
    float2 v = bfpair(((const unsigned*)(h + (size_t)node * 128))[lane]);
    float sc = dd * dd;
    float accx = v.x * sc, accy = v.y * sc;
    int j = rowptr[node];
    const int end = rowptr[node + 1];
    for (; j + 3 < end; j += 4) {
        int s0 = ssrc[j], s1 = ssrc[j + 1], s2 = ssrc[j + 2], s3 = ssrc[j + 3];
        float n0 = dinv[s0] * dd, n1 = dinv[s1] * dd;
        float n2 = dinv[s2] * dd, n3 = dinv[s3] * dd;
        float2 v0 = bfpair(((const unsigned*)(h + (size_t)s0 * 128))[lane]);
        float2 v1 = bfpair(((const unsigned*)(h + (size_t)s1 * 128))[lane]);
        float2 v2 = bfpair(((const unsigned*)(h + (size_t)s2 * 128))[lane]);
        float2 v3 = bfpair(((const unsigned*)(h + (size_t)s3 * 128))[lane]);
        accx += v0.x * n0 + v1.x * n1 + v2.x * n2 + v3.x * n3;
        accy += v0.y * n0 + v1.y * n1 + v2.y * n2 + v3.y * n3;
    }
    for (; j < end; ++j) {
        int s0 = ssrc[j];
        float n0 = dinv[s0] * dd;
        float2 v0 = bfpair(((const unsigned*)(h + (size_t)s0 * 128))[lane]);
        accx += v0.x * n0;
        accy += v0.y * n0;
    }
    float2 b = ((const float2*)bias)[lane];
    accx = fmaxf(accx + b.x, 0.f);
    accy = fmaxf(accy + b.y, 0.f);
    // FC: lane covers k = 2*lane, 2*lane+1 ; Wfc is [128][2] row-major
    int k0 = lane * 2;
    float a0 = accx * Wfc[k0 * 2 + 0] + accy * Wfc[(k0 + 1) * 2 + 0];
    float a1 = accx * Wfc[k0 * 2 + 1] + accy * Wfc[(k0 + 1) * 2 + 1];
#pragma unroll
    for (int off = 32; off > 0; off >>= 1) {
        a0 += __shfl_down(a0, off);
        a1 += __shfl_down(a1, off);
    }
    if (lane == 0) {
        float l0 = a0 + bfc[0];
        float l1 = a1 + bfc[1];
        float m = fmaxf(l0, l1);
        float lse = m + logf(expf(l0 - m) + expf(l1 - m));
        out[(size_t)node * 2 + 0] = l0 - lse;
        out[(size_t)node * 2 + 1] = l1 - lse;
    }
}

extern "C" void kernel_launch(void* const* d_in, const int* in_sizes, int n_in,
                              void* d_out, int out_size, void* d_ws, size_t ws_size,
                              hipStream_t stream) {
    const float* x   = (const float*)d_in[0];
    const int*   ei  = (const int*)d_in[1];
    const float* W1  = (const float*)d_in[2];
    const float* b1  = (const float*)d_in[3];
    const float* W2  = (const float*)d_in[4];
    const float* b2  = (const float*)d_in[5];
    const float* Wfc = (const float*)d_in[6];
    const float* bfc = (const float*)d_in[7];
    float* out = (float*)d_out;

    const int* src = ei;
    const int* dst = ei + E_EDGES;

    // workspace: 256B-aligned carve
    char* wp = (char*)d_ws;
    auto carve = [&](size_t bytes) -> char* {
        char* p = wp;
        wp += (bytes + 255) & ~(size_t)255;
        return p;
    };
    int*    cnt    = (int*)carve(N_NODES * 4);
    int*    rowptr = (int*)carve((N_NODES + 1) * 4);
    int*    cursor = (int*)carve(N_NODES * 4);
    int*    bsum   = (int*)carve(128 * 4);
    int*    ssrc   = (int*)carve((size_t)E_EDGES * 4);
    float*  dinv   = (float*)carve(N_NODES * 4);
    bf16_t* hbuf   = (bf16_t*)carve((size_t)N_NODES * FDIM * 2);
    bf16_t* x2buf  = (bf16_t*)carve((size_t)N_NODES * FDIM * 2);
    bf16_t* Wt1    = (bf16_t*)carve(128 * 128 * 2);
    bf16_t* Wt2    = (bf16_t*)carve(128 * 128 * 2);

    const int NN_BLK = (N_NODES + 255) / 256;
    const int NODE_WAVE_BLK = (N_NODES * 64 + 255) / 256;
    const int EDGE_PASS_BLK = ((E_EDGES + 255) / 256) * NPASS;   // 50000
    const int GEMM_BLK = (N_NODES + 63) / 64;                     // 1563

    // ---- build CSR (dst-sorted) + dinv ----
    hipMemsetAsync(cnt, 0, N_NODES * sizeof(int), stream);
    hipMemsetAsync(cursor, 0, N_NODES * sizeof(int), stream);
    hist_kernel<<<EDGE_PASS_BLK, 256, 0, stream>>>(dst, cnt);
    scan1<<<NSCAN_BLKS, 256, 0, stream>>>(cnt, rowptr, bsum);
    scan2<<<1, 128, 0, stream>>>(bsum);
    scan3<<<NN_BLK, 256, 0, stream>>>(rowptr, bsum, cnt, dinv);
    scatter_kernel<<<EDGE_PASS_BLK, 256, 0, stream>>>(src, dst, rowptr, cursor, ssrc);

    // ---- weight transpose/convert ----
    wcvt_kernel<<<64, 256, 0, stream>>>(W1, Wt1);
    wcvt_kernel<<<64, 256, 0, stream>>>(W2, Wt2);

    // ---- layer 1 ----
    gemm_mfma<true><<<GEMM_BLK, 256, 0, stream>>>(x, Wt1, hbuf);
    agg_kernel<<<NODE_WAVE_BLK, 256, 0, stream>>>(rowptr, ssrc, dinv, hbuf, b1, x2buf);

    // ---- layer 2 (agg fused with FC + log_softmax) ----
    gemm_mfma<false><<<GEMM_BLK, 256, 0, stream>>>(x2buf, Wt2, hbuf);
    agg_fc_kernel<<<NODE_WAVE_BLK, 256, 0, stream>>>(rowptr, ssrc, dinv, hbuf, b2,
                                                     Wfc, bfc, out);
}